// Round 13
// baseline (111.266 us; speedup 1.0000x reference)
//
#include <hip/hip_runtime.h>
#include <math.h>

// ---------------------------------------------------------------------------
// Refine_Attn: 3-level neighborhood-attention pyramid, fp32.
// Stage 1: C=32,  24x48 | Stage 2: C=64, 48x96 | Stage 3: C=128, 96x192
//
// Identities used:
//  - up2x(y) @ Wup + bup feeds only the next qkv matmul ->
//      qkv = up2x(y) @ (Wup@Wqkv) + (bup@Wqkv + bqkv)   (composed on device)
//  - stage 1 is small enough to run qkv+attention+proj in ONE kernel with a
//    halo-redundant qkv computed in LDS.
// Launch plan (6 dispatches):
//   compose2 -> fused_s1 -> qkvup2(UP-GEMM) -> na2d_proj2
//            -> qkvup3(UP-GEMM) -> na2d_proj3 (CHW out)
// ---------------------------------------------------------------------------

// Weight composition: Wc = Wup @ Wqkv, bc = bup @ Wqkv + bqkv (both stages).
__global__ void compose2(const float* __restrict__ Wu1, const float* __restrict__ bu1,
                         const float* __restrict__ Wq2, const float* __restrict__ bq2,
                         const float* __restrict__ Wu2, const float* __restrict__ bu2,
                         const float* __restrict__ Wq3, const float* __restrict__ bq3,
                         float* __restrict__ Wc1, float* __restrict__ bc1,
                         float* __restrict__ Wc2, float* __restrict__ bc2) {
    int idx = blockIdx.x * blockDim.x + threadIdx.x;
    const int R1 = 33 * 192;           // 32 weight rows + 1 bias row
    if (idx < R1) {
        const int r = idx / 192;
        const int n = idx - r * 192;
        const float* wp = Wq2 + n;
        const float* a  = (r < 32) ? Wu1 + r * 64 : bu1;
        float s = 0.f;
        for (int k = 0; k < 64; ++k) s = fmaf(a[k], wp[(size_t)k * 192], s);
        if (r < 32) Wc1[r * 192 + n] = s;
        else        bc1[n] = s + bq2[n];
    } else {
        idx -= R1;
        if (idx >= 65 * 384) return;
        const int r = idx / 384;
        const int n = idx - r * 384;
        const float* wp = Wq3 + n;
        const float* a  = (r < 64) ? Wu2 + r * 128 : bu2;
        float s = 0.f;
        for (int k = 0; k < 128; ++k) s = fmaf(a[k], wp[(size_t)k * 384], s);
        if (r < 64) Wc2[r * 384 + n] = s;
        else        bc2[n] = s + bq3[n];
    }
}

// ---- Fused stage 1 (C=32, H=24, W=48): qkv + neighborhood attn + proj ----
// Block = 16 consecutive pixels of one row. Halo = 5 rows x 20 cols of qkv
// computed redundantly in LDS from the CHW input. 256 threads.
__global__ __launch_bounds__(256) void fused_s1(
        const float* __restrict__ x,    // CHW (32, 1152)
        const float* __restrict__ Wq,   // 32x96
        const float* __restrict__ bq,   // 96
        const float* __restrict__ rpb,  // 9x9
        const float* __restrict__ Wp,   // 32x32
        const float* __restrict__ bp,   // 32
        float* __restrict__ y) {        // HWC (1152, 32)
    const int H = 24, W = 48, M = 1152;
    __shared__ float xh[100][32];       // halo x (slot = ir*20+jc)
    __shared__ float wq_s[32][96];
    __shared__ float qkvh[100][100];    // halo qkv (96 used; stride 100 = 16B-aligned, bank-spread)
    __shared__ float att_s[16][36];
    __shared__ float wp_s[32][32];

    const int tid  = threadIdx.x;
    const int pix0 = blockIdx.x * 16;
    const int hrow = pix0 / W;
    const int wb   = pix0 - hrow * W;   // 16 | 48 so the block is one row segment
    const int r0   = min(max(hrow - 2, 0), H - 5);
    const int c0   = wb - 2;            // slot j -> col c0+j (may be out of range; guarded)

    // stage weights + x halo
    for (int i = tid; i < 32 * 96; i += 256) ((float*)wq_s)[i] = Wq[i];
    for (int i = tid; i < 32 * 32; i += 256) ((float*)wp_s)[i] = Wp[i];
    for (int i = tid; i < 3200; i += 256) {
        const int c = i / 100;          // channel
        const int s = i - c * 100;      // slot
        const int ir = s / 20, jc = s - ir * 20;
        const int col = c0 + jc;
        float v = 0.f;
        if (col >= 0 && col < W) v = x[(size_t)c * M + (r0 + ir) * W + col];
        xh[s][c] = v;
    }
    __syncthreads();

    // qkv for the halo: 100 px x 96, K=32 (col-quads per thread)
    const float qscale = 0.17677669529663687f;  // 1/sqrt(32)
    for (int i = tid; i < 100 * 24; i += 256) {
        const int s  = i / 24;
        const int n4 = (i - s * 24) * 4;
        float4 acc = *(const float4*)&bq[n4];
        for (int k = 0; k < 32; ++k) {
            const float xv = xh[s][k];
            const float4 wv = *(const float4*)&wq_s[k][n4];
            acc.x = fmaf(xv, wv.x, acc.x);
            acc.y = fmaf(xv, wv.y, acc.y);
            acc.z = fmaf(xv, wv.z, acc.z);
            acc.w = fmaf(xv, wv.w, acc.w);
        }
        if (n4 < 32) { acc.x *= qscale; acc.y *= qscale; acc.z *= qscale; acc.w *= qscale; }
        *(float4*)&qkvh[s][n4] = acc;
    }
    __syncthreads();

    // attention: 4 waves x 4 pixels, 16-lane channel groups (VPL=2)
    const int lane = tid & 63;
    const int g    = lane >> 4;
    const int li   = lane & 15;
    const int wave = tid >> 6;
    const int lp   = wave * 4 + g;           // local pixel 0..15
    const int w    = wb + lp;
    const int w0p  = min(max(w - 2, 0), W - 5);
    const int cs0  = w0p - c0;               // col slot base (0..15)
    const int cb   = li * 2;
    const int sown = (hrow - r0) * 20 + (lp + 2);
    const float q0 = qkvh[sown][cb];
    const float q1 = qkvh[sown][cb + 1];
    const int bih = r0 - hrow + 4;
    const int biw = w0p - w + 4;

    float p[25];
#pragma unroll
    for (int jr = 0; jr < 5; ++jr)
#pragma unroll
        for (int jc = 0; jc < 5; ++jc) {
            const int s = jr * 20 + cs0 + jc;
            p[jr * 5 + jc] = fmaf(q0, qkvh[s][32 + cb], q1 * qkvh[s][32 + cb + 1]);
        }
#pragma unroll
    for (int j = 0; j < 25; ++j) {
        float v = p[j];
        v += __shfl_xor(v, 1);
        v += __shfl_xor(v, 2);
        v += __shfl_xor(v, 4);
        v += __shfl_xor(v, 8);
        p[j] = v + rpb[(bih + j / 5) * 9 + (biw + j % 5)];
    }
    float mx = p[0];
#pragma unroll
    for (int j = 1; j < 25; ++j) mx = fmaxf(mx, p[j]);
    float sum = 0.f;
#pragma unroll
    for (int j = 0; j < 25; ++j) {
        p[j] = expf(p[j] - mx);
        sum += p[j];
    }
    const float inv = 1.f / sum;
    float a0 = 0.f, a1 = 0.f;
#pragma unroll
    for (int jr = 0; jr < 5; ++jr)
#pragma unroll
        for (int jc = 0; jc < 5; ++jc) {
            const int s = jr * 20 + cs0 + jc;
            const float pj = p[jr * 5 + jc];
            a0 = fmaf(pj, qkvh[s][64 + cb], a0);
            a1 = fmaf(pj, qkvh[s][64 + cb + 1], a1);
        }
    att_s[lp][cb]     = a0 * inv;
    att_s[lp][cb + 1] = a1 * inv;
    __syncthreads();

    // proj: 16x32 @ 32x32 + bias
    const int tm = tid & 15;
    const int tn = tid >> 4;
    float acc0 = bp[tn * 2];
    float acc1 = bp[tn * 2 + 1];
    for (int k = 0; k < 32; ++k) {
        const float av = att_s[tm][k];
        acc0 = fmaf(av, wp_s[k][tn * 2], acc0);
        acc1 = fmaf(av, wp_s[k][tn * 2 + 1], acc1);
    }
    float* op = y + (size_t)(pix0 + tm) * 32 + tn * 2;
    op[0] = acc0;
    op[1] = acc1;
}

// Register-tiled GEMM with optional fused bilinear-2x A ("UP").
template <int BM, int BN, int NT, int TRANS, int UP>
__global__ __launch_bounds__(256) void gemm_rt(
        const float* __restrict__ A, const float* __restrict__ Wt,
        const float* __restrict__ bias, float* __restrict__ out,
        int M, int K, int N, int qcols, float qscale, int Hs, int Ws) {
    constexpr int BK = 16;
    constexpr int RT = BM / 16;
    constexpr int AIT = (BM * BK) / (4 * 256);
    constexpr int BIT = (BK * BN) / (4 * 256);
    __shared__ float As[BK][BM + 4];
    __shared__ float Bs[BK][BN + 4];
    const int tid = threadIdx.x;
    const int tn = tid >> 4;
    const int tm = tid & 15;
    const int m0 = blockIdx.x * BM;
    const int n0 = blockIdx.y * BN;

    const int sa_m = tid >> 2;
    const int sa_k = (tid & 3) << 2;

    const float* ybase[AIT][4];
    float uwh[AIT], uww[AIT];
    if (UP) {
        const int Wd = 2 * Ws, Hd = 2 * Hs;
#pragma unroll
        for (int i = 0; i < AIT; ++i) {
            const int row = m0 + sa_m + i * 64;
            const int h2 = row / Wd;
            const int w2 = row - h2 * Wd;
            const float ph = (float)h2 * (float)(Hs - 1) / (float)(Hd - 1);
            const int h0i = (int)ph;
            const int h1i = min(h0i + 1, Hs - 1);
            uwh[i] = ph - (float)h0i;
            const float pw = (float)w2 * (float)(Ws - 1) / (float)(Wd - 1);
            const int w0i = (int)pw;
            const int w1i = min(w0i + 1, Ws - 1);
            uww[i] = pw - (float)w0i;
            ybase[i][0] = A + ((size_t)h0i * Ws + w0i) * K;
            ybase[i][1] = A + ((size_t)h0i * Ws + w1i) * K;
            ybase[i][2] = A + ((size_t)h1i * Ws + w0i) * K;
            ybase[i][3] = A + ((size_t)h1i * Ws + w1i) * K;
        }
    }

    float acc[RT][NT];
#pragma unroll
    for (int r = 0; r < RT; ++r)
#pragma unroll
        for (int c = 0; c < NT; ++c) acc[r][c] = 0.f;

    for (int k0 = 0; k0 < K; k0 += BK) {
        float4 av[AIT];
#pragma unroll
        for (int i = 0; i < AIT; ++i) {
            if (UP) {
                const float4 v00 = *(const float4*)(ybase[i][0] + k0 + sa_k);
                const float4 v01 = *(const float4*)(ybase[i][1] + k0 + sa_k);
                const float4 v10 = *(const float4*)(ybase[i][2] + k0 + sa_k);
                const float4 v11 = *(const float4*)(ybase[i][3] + k0 + sa_k);
                const float wh = uwh[i], ww = uww[i];
                av[i].x = (v00.x * (1.f - wh) + v10.x * wh) * (1.f - ww) +
                          (v01.x * (1.f - wh) + v11.x * wh) * ww;
                av[i].y = (v00.y * (1.f - wh) + v10.y * wh) * (1.f - ww) +
                          (v01.y * (1.f - wh) + v11.y * wh) * ww;
                av[i].z = (v00.z * (1.f - wh) + v10.z * wh) * (1.f - ww) +
                          (v01.z * (1.f - wh) + v11.z * wh) * ww;
                av[i].w = (v00.w * (1.f - wh) + v10.w * wh) * (1.f - ww) +
                          (v01.w * (1.f - wh) + v11.w * wh) * ww;
            } else {
                av[i] = *(const float4*)(A + (size_t)(m0 + sa_m + i * 64) * K + k0 + sa_k);
            }
        }
        float4 bv[BIT];
#pragma unroll
        for (int i = 0; i < BIT; ++i) {
            const int f  = tid + i * 256;
            const int kl = f / (BN / 4);
            const int n4 = f - kl * (BN / 4);
            bv[i] = *(const float4*)(Wt + (size_t)(k0 + kl) * N + n0 + n4 * 4);
        }
        __syncthreads();
#pragma unroll
        for (int i = 0; i < AIT; ++i) {
            As[sa_k + 0][sa_m + i * 64] = av[i].x;
            As[sa_k + 1][sa_m + i * 64] = av[i].y;
            As[sa_k + 2][sa_m + i * 64] = av[i].z;
            As[sa_k + 3][sa_m + i * 64] = av[i].w;
        }
#pragma unroll
        for (int i = 0; i < BIT; ++i) {
            const int f  = tid + i * 256;
            const int kl = f / (BN / 4);
            const int n4 = f - kl * (BN / 4);
            *(float4*)&Bs[kl][n4 * 4] = bv[i];
        }
        __syncthreads();
#pragma unroll
        for (int kk = 0; kk < BK; ++kk) {
            float a[RT];
#pragma unroll
            for (int q = 0; q < RT / 4; ++q) {
                float4 t = *(const float4*)&As[kk][tm * RT + q * 4];
                a[q * 4 + 0] = t.x; a[q * 4 + 1] = t.y;
                a[q * 4 + 2] = t.z; a[q * 4 + 3] = t.w;
            }
            float b[NT];
#pragma unroll
            for (int q = 0; q < NT / 4; ++q) {
                float4 t = *(const float4*)&Bs[kk][tn * NT + q * 4];
                b[q * 4 + 0] = t.x; b[q * 4 + 1] = t.y;
                b[q * 4 + 2] = t.z; b[q * 4 + 3] = t.w;
            }
#pragma unroll
            for (int r = 0; r < RT; ++r)
#pragma unroll
                for (int c = 0; c < NT; ++c)
                    acc[r][c] = fmaf(a[r], b[c], acc[r][c]);
        }
    }

#pragma unroll
    for (int c = 0; c < NT; ++c) {
        const int n = n0 + tn * NT + c;
        const float bz = bias[n];
        const float sc = (n < qcols) ? qscale : 1.f;
#pragma unroll
        for (int r = 0; r < RT; ++r) acc[r][c] = (acc[r][c] + bz) * sc;
    }
    if (TRANS) {
#pragma unroll
        for (int c = 0; c < NT; ++c) {
            const int n = n0 + tn * NT + c;
            float* op = out + (size_t)n * M + m0 + tm * RT;
#pragma unroll
            for (int q = 0; q < RT / 4; ++q)
                *(float4*)(op + q * 4) = make_float4(acc[q * 4][c], acc[q * 4 + 1][c],
                                                     acc[q * 4 + 2][c], acc[q * 4 + 3][c]);
        }
    } else {
#pragma unroll
        for (int r = 0; r < RT; ++r) {
            float* op = out + (size_t)(m0 + tm * RT + r) * N + n0 + tn * NT;
#pragma unroll
            for (int q = 0; q < NT / 4; ++q)
                *(float4*)(op + q * 4) = make_float4(acc[r][q * 4], acc[r][q * 4 + 1],
                                                     acc[r][q * 4 + 2], acc[r][q * 4 + 3]);
        }
    }
}

template <int VPL>
__device__ inline void loadv(const float* __restrict__ p, float* d) {
    if constexpr (VPL == 2) {
        float2 t = *(const float2*)p;
        d[0] = t.x; d[1] = t.y;
    } else if constexpr (VPL == 4) {
        float4 t = *(const float4*)p;
        d[0] = t.x; d[1] = t.y; d[2] = t.z; d[3] = t.w;
    } else {
        float4 t0 = *(const float4*)p;
        float4 t1 = *(const float4*)(p + 4);
        d[0] = t0.x; d[1] = t0.y; d[2] = t0.z; d[3] = t0.w;
        d[4] = t1.x; d[5] = t1.y; d[6] = t1.z; d[7] = t1.w;
    }
}

// Fused neighborhood attention + proj (stages 2/3). 256 thr = 4 waves x 4 px.
template <int C, int TRANS>
__global__ __launch_bounds__(256) void na2d_proj(
        const float* __restrict__ qkv, const float* __restrict__ rpb,
        const float* __restrict__ Wp, const float* __restrict__ bp,
        float* __restrict__ out, int H, int W, int M) {
    constexpr int VPL = C / 16;
    constexpr int NT  = C / 16;
    __shared__ float att_s[16][C + 4];
    __shared__ float Bs[16][C];
    const int tid  = threadIdx.x;
    const int lane = tid & 63;
    const int g    = lane >> 4;
    const int li   = lane & 15;
    const int wave = tid >> 6;
    const int lp   = wave * 4 + g;
    const int pix  = blockIdx.x * 16 + lp;
    const int h = pix / W;
    const int w = pix - h * W;
    const int h0 = min(max(h - 2, 0), H - 5);
    const int w0 = min(max(w - 2, 0), W - 5);
    const int cb = li * VPL;
    const int bih = h0 - h + 4;
    const int biw = w0 - w + 4;

    float qf[VPL];
    loadv<VPL>(qkv + (size_t)pix * (3 * C) + cb, qf);

    float p[25];
#pragma unroll
    for (int jr = 0; jr < 5; ++jr) {
        const float* rowk = qkv + (size_t)((h0 + jr) * W + w0) * (3 * C) + C + cb;
        float kf[5][VPL];
#pragma unroll
        for (int jc = 0; jc < 5; ++jc) loadv<VPL>(rowk + jc * 3 * C, kf[jc]);
#pragma unroll
        for (int jc = 0; jc < 5; ++jc) {
            float s = qf[0] * kf[jc][0];
#pragma unroll
            for (int v = 1; v < VPL; ++v) s = fmaf(qf[v], kf[jc][v], s);
            p[jr * 5 + jc] = s;
        }
    }
#pragma unroll
    for (int jr = 0; jr < 5; ++jr)
#pragma unroll
        for (int jc = 0; jc < 5; ++jc) {
            const int j = jr * 5 + jc;
            float v = p[j];
            v += __shfl_xor(v, 1);
            v += __shfl_xor(v, 2);
            v += __shfl_xor(v, 4);
            v += __shfl_xor(v, 8);
            p[j] = v + rpb[(bih + jr) * 9 + (biw + jc)];
        }
    float mx = p[0];
#pragma unroll
    for (int j = 1; j < 25; ++j) mx = fmaxf(mx, p[j]);
    float sum = 0.f;
#pragma unroll
    for (int j = 0; j < 25; ++j) {
        p[j] = expf(p[j] - mx);
        sum += p[j];
    }
    const float inv = 1.f / sum;

    float a[VPL];
#pragma unroll
    for (int v = 0; v < VPL; ++v) a[v] = 0.f;
#pragma unroll
    for (int jr = 0; jr < 5; ++jr) {
        const float* rowv = qkv + (size_t)((h0 + jr) * W + w0) * (3 * C) + 2 * C + cb;
        float vf[5][VPL];
#pragma unroll
        for (int jc = 0; jc < 5; ++jc) loadv<VPL>(rowv + jc * 3 * C, vf[jc]);
#pragma unroll
        for (int jc = 0; jc < 5; ++jc)
#pragma unroll
            for (int v = 0; v < VPL; ++v) a[v] = fmaf(p[jr * 5 + jc], vf[jc][v], a[v]);
    }
#pragma unroll
    for (int v = 0; v < VPL; ++v) att_s[lp][cb + v] = a[v] * inv;

    const int tm = tid & 15;
    const int tn = tid >> 4;
    constexpr int WPT = C / 16;
    const int skl = tid >> 4;
    const int snn = (tid & 15) * WPT;
    float acc[NT];
#pragma unroll
    for (int c = 0; c < NT; ++c) acc[c] = bp[tn * NT + c];

    for (int k0 = 0; k0 < C; k0 += 16) {
        float tmp[WPT];
        {
            const float* src = Wp + (size_t)(k0 + skl) * C + snn;
#pragma unroll
            for (int t = 0; t < WPT; ++t) tmp[t] = src[t];
        }
        __syncthreads();
#pragma unroll
        for (int t = 0; t < WPT; ++t) Bs[skl][snn + t] = tmp[t];
        __syncthreads();
#pragma unroll
        for (int kk = 0; kk < 16; ++kk) {
            const float av = att_s[tm][k0 + kk];
            const float* bsp = &Bs[kk][tn * NT];
#pragma unroll
            for (int c = 0; c < NT; ++c) acc[c] = fmaf(av, bsp[c], acc[c]);
        }
    }

    const int m0 = blockIdx.x * 16;
    if (TRANS) {
#pragma unroll
        for (int c = 0; c < NT; ++c)
            out[(size_t)(tn * NT + c) * M + m0 + tm] = acc[c];
    } else {
        float* op = out + (size_t)(m0 + tm) * C + tn * NT;
#pragma unroll
        for (int c = 0; c < NT; ++c) op[c] = acc[c];
    }
}

extern "C" void kernel_launch(void* const* d_in, const int* in_sizes, int n_in,
                              void* d_out, int out_size, void* d_ws, size_t ws_size,
                              hipStream_t stream) {
    const float* attn    = (const float*)d_in[0];
    const float* w_qkv1  = (const float*)d_in[1];
    const float* b_qkv1  = (const float*)d_in[2];
    const float* w_proj1 = (const float*)d_in[3];
    const float* b_proj1 = (const float*)d_in[4];
    const float* rpb1    = (const float*)d_in[5];
    const float* w_qkv2  = (const float*)d_in[6];
    const float* b_qkv2  = (const float*)d_in[7];
    const float* w_proj2 = (const float*)d_in[8];
    const float* b_proj2 = (const float*)d_in[9];
    const float* rpb2    = (const float*)d_in[10];
    const float* w_qkv3  = (const float*)d_in[11];
    const float* b_qkv3  = (const float*)d_in[12];
    const float* w_proj3 = (const float*)d_in[13];
    const float* b_proj3 = (const float*)d_in[14];
    const float* rpb3    = (const float*)d_in[15];
    const float* w_up1   = (const float*)d_in[16];
    const float* b_up1   = (const float*)d_in[17];
    const float* w_up2   = (const float*)d_in[18];
    const float* b_up2   = (const float*)d_in[19];
    float* out = (float*)d_out;

    float* ws   = (float*)d_ws;
    float* bufB = ws + 2359296;              // qkv   (max 18432*384)
    float* bufD = bufB + 7077888;            // y     (max 4608*64)
    float* wc1  = bufD + 294912;             // 32x192 composed up1->qkv2
    float* bc1  = wc1 + 6144;                // 192
    float* wc2  = bc1 + 192;                 // 64x384 composed up2->qkv3
    float* bc2  = wc2 + 24576;               // 384

    // weight composition (weights only)
    compose2<<<(33 * 192 + 65 * 384 + 255) / 256, 256, 0, stream>>>(
        w_up1, b_up1, w_qkv2, b_qkv2, w_up2, b_up2, w_qkv3, b_qkv3,
        wc1, bc1, wc2, bc2);

    // ---- Stage 1: fully fused (qkv + attn + proj) ----
    fused_s1<<<72, 256, 0, stream>>>(attn, w_qkv1, b_qkv1, rpb1,
                                     w_proj1, b_proj1, bufD);

    // ---- Stage 2: C=64, 48x96, M=4608; qkv2 = up2x(y1) @ wc1 + bc1 ----
    {
        const int H = 48, W = 96, C = 64, M = H * W;
        gemm_rt<64, 64, 4, 0, 1><<<dim3(M / 64, 3), 256, 0, stream>>>(
            bufD, wc1, bc1, bufB, M, 32, 3 * C, C, 1.f / sqrtf((float)C), 24, 48);
        na2d_proj<64, 0><<<M / 16, 256, 0, stream>>>(
            bufB, rpb2, w_proj2, b_proj2, bufD, H, W, M);
    }
    // ---- Stage 3: C=128, 96x192, M=18432; qkv3 = up2x(y2) @ wc2 + bc2 ----
    {
        const int H = 96, W = 192, C = 128, M = H * W;
        gemm_rt<128, 128, 8, 0, 1><<<dim3(M / 128, 3), 256, 0, stream>>>(
            bufD, wc2, bc2, bufB, M, 64, 3 * C, C, 1.f / sqrtf((float)C), 48, 96);
        na2d_proj<128, 1><<<M / 16, 256, 0, stream>>>(
            bufB, rpb3, w_proj3, b_proj3, out, H, W, M);  // -> CHW
    }
}

// Round 15
// 108.895 us; speedup vs baseline: 1.0218x; 1.0218x over previous
//
#include <hip/hip_runtime.h>
#include <math.h>

// ---------------------------------------------------------------------------
// Refine_Attn: 3-level neighborhood-attention pyramid, fp32.
// Stage 1: C=32,  24x48 | Stage 2: C=64, 48x96 | Stage 3: C=128, 96x192
//
// Identities: up2x(y)@Wup+bup feeds only the next qkv matmul ->
//   qkv = up2x(y) @ (Wup@Wqkv) + (bup@Wqkv + bqkv)   (composed on device).
// Launch plan (7 dispatches):
//   compose2 -> qkv1(mm,CHW) -> na2d_proj1 -> qkvup2(UP-GEMM) -> na2d_proj2
//            -> qkvup3(UP-GEMM) -> na2d_proj3 (CHW out)
// R13 lesson: full stage-1 fusion (halo-redundant qkv in LDS) REGRESSED
// (-3us, low occupancy @71KB LDS) -> reverted to two small kernels.
// This round: XCD-aware block swizzle (L2 locality for the 25x K/V reuse)
// + BK=32 proj tiles (half the barriers).
// ---------------------------------------------------------------------------

__device__ inline int xcd_swz(int bid, int n) {
    // bijective when n % 8 == 0 (all our grids are)
    return (n % 8 == 0) ? (bid % 8) * (n / 8) + bid / 8 : bid;
}

// Weight composition: Wc = Wup @ Wqkv, bc = bup @ Wqkv + bqkv (both stages).
__global__ void compose2(const float* __restrict__ Wu1, const float* __restrict__ bu1,
                         const float* __restrict__ Wq2, const float* __restrict__ bq2,
                         const float* __restrict__ Wu2, const float* __restrict__ bu2,
                         const float* __restrict__ Wq3, const float* __restrict__ bq3,
                         float* __restrict__ Wc1, float* __restrict__ bc1,
                         float* __restrict__ Wc2, float* __restrict__ bc2) {
    int idx = blockIdx.x * blockDim.x + threadIdx.x;
    const int R1 = 33 * 192;           // 32 weight rows + 1 bias row
    if (idx < R1) {
        const int r = idx / 192;
        const int n = idx - r * 192;
        const float* wp = Wq2 + n;
        const float* a  = (r < 32) ? Wu1 + r * 64 : bu1;
        float s = 0.f;
        for (int k = 0; k < 64; ++k) s = fmaf(a[k], wp[(size_t)k * 192], s);
        if (r < 32) Wc1[r * 192 + n] = s;
        else        bc1[n] = s + bq2[n];
    } else {
        idx -= R1;
        if (idx >= 65 * 384) return;
        const int r = idx / 384;
        const int n = idx - r * 384;
        const float* wp = Wq3 + n;
        const float* a  = (r < 64) ? Wu2 + r * 128 : bu2;
        float s = 0.f;
        for (int k = 0; k < 128; ++k) s = fmaf(a[k], wp[(size_t)k * 384], s);
        if (r < 64) Wc2[r * 384 + n] = s;
        else        bc2[n] = s + bq3[n];
    }
}

// Small-matrix broadcast matmul (stage-1 qkv only).
// CHW: A is (K, HW); gather A[m][k] = A[k*HW+m] during staging.
template <int MT, int CHW>
__global__ void mm_bias(const float* __restrict__ A, const float* __restrict__ Wt,
                        const float* __restrict__ bias, float* __restrict__ out,
                        int M, int K, int N, int qcols, float qscale) {
    extern __shared__ float As[];  // MT*K floats
    const int m0 = blockIdx.x * MT;
    const int n  = threadIdx.x;
    if (CHW) {
        for (int idx = n; idx < MT * K; idx += blockDim.x) {
            const int r = idx / K;
            const int k = idx - r * K;
            As[idx] = A[(size_t)k * M + m0 + r];
        }
    } else {
        const float4* src = (const float4*)(A + (size_t)m0 * K);
        float4* dst = (float4*)As;
        for (int idx = n; idx < MT * K / 4; idx += blockDim.x) dst[idx] = src[idx];
    }
    __syncthreads();

    float acc[MT];
#pragma unroll
    for (int r = 0; r < MT; ++r) acc[r] = bias[n];
    for (int k = 0; k < K; k += 4) {
        const float* wp = Wt + (size_t)k * N + n;
        const float w0 = wp[0];
        const float w1 = wp[N];
        const float w2 = wp[2 * N];
        const float w3 = wp[3 * N];
#pragma unroll
        for (int r = 0; r < MT; ++r) {
            float4 a4 = *(const float4*)&As[r * K + k];
            acc[r] = fmaf(a4.x, w0, acc[r]);
            acc[r] = fmaf(a4.y, w1, acc[r]);
            acc[r] = fmaf(a4.z, w2, acc[r]);
            acc[r] = fmaf(a4.w, w3, acc[r]);
        }
    }
    if (n < qcols) {
#pragma unroll
        for (int r = 0; r < MT; ++r) acc[r] *= qscale;
    }
#pragma unroll
    for (int r = 0; r < MT; ++r) out[(size_t)(m0 + r) * N + n] = acc[r];
}

// Register-tiled GEMM with optional fused bilinear-2x A ("UP").
template <int BM, int BN, int NT, int TRANS, int UP>
__global__ __launch_bounds__(256) void gemm_rt(
        const float* __restrict__ A, const float* __restrict__ Wt,
        const float* __restrict__ bias, float* __restrict__ out,
        int M, int K, int N, int qcols, float qscale, int Hs, int Ws) {
    constexpr int BK = 16;
    constexpr int RT = BM / 16;
    constexpr int AIT = (BM * BK) / (4 * 256);
    constexpr int BIT = (BK * BN) / (4 * 256);
    __shared__ float As[BK][BM + 4];
    __shared__ float Bs[BK][BN + 4];
    const int tid = threadIdx.x;
    const int tn = tid >> 4;
    const int tm = tid & 15;
    const int bx = xcd_swz(blockIdx.x, gridDim.x);   // L2 locality across XCDs
    const int m0 = bx * BM;
    const int n0 = blockIdx.y * BN;

    const int sa_m = tid >> 2;
    const int sa_k = (tid & 3) << 2;

    const float* ybase[AIT][4];
    float uwh[AIT], uww[AIT];
    if (UP) {
        const int Wd = 2 * Ws, Hd = 2 * Hs;
#pragma unroll
        for (int i = 0; i < AIT; ++i) {
            const int row = m0 + sa_m + i * 64;
            const int h2 = row / Wd;
            const int w2 = row - h2 * Wd;
            const float ph = (float)h2 * (float)(Hs - 1) / (float)(Hd - 1);
            const int h0i = (int)ph;
            const int h1i = min(h0i + 1, Hs - 1);
            uwh[i] = ph - (float)h0i;
            const float pw = (float)w2 * (float)(Ws - 1) / (float)(Wd - 1);
            const int w0i = (int)pw;
            const int w1i = min(w0i + 1, Ws - 1);
            uww[i] = pw - (float)w0i;
            ybase[i][0] = A + ((size_t)h0i * Ws + w0i) * K;
            ybase[i][1] = A + ((size_t)h0i * Ws + w1i) * K;
            ybase[i][2] = A + ((size_t)h1i * Ws + w0i) * K;
            ybase[i][3] = A + ((size_t)h1i * Ws + w1i) * K;
        }
    }

    float acc[RT][NT];
#pragma unroll
    for (int r = 0; r < RT; ++r)
#pragma unroll
        for (int c = 0; c < NT; ++c) acc[r][c] = 0.f;

    for (int k0 = 0; k0 < K; k0 += BK) {
        float4 av[AIT];
#pragma unroll
        for (int i = 0; i < AIT; ++i) {
            if (UP) {
                const float4 v00 = *(const float4*)(ybase[i][0] + k0 + sa_k);
                const float4 v01 = *(const float4*)(ybase[i][1] + k0 + sa_k);
                const float4 v10 = *(const float4*)(ybase[i][2] + k0 + sa_k);
                const float4 v11 = *(const float4*)(ybase[i][3] + k0 + sa_k);
                const float wh = uwh[i], ww = uww[i];
                av[i].x = (v00.x * (1.f - wh) + v10.x * wh) * (1.f - ww) +
                          (v01.x * (1.f - wh) + v11.x * wh) * ww;
                av[i].y = (v00.y * (1.f - wh) + v10.y * wh) * (1.f - ww) +
                          (v01.y * (1.f - wh) + v11.y * wh) * ww;
                av[i].z = (v00.z * (1.f - wh) + v10.z * wh) * (1.f - ww) +
                          (v01.z * (1.f - wh) + v11.z * wh) * ww;
                av[i].w = (v00.w * (1.f - wh) + v10.w * wh) * (1.f - ww) +
                          (v01.w * (1.f - wh) + v11.w * wh) * ww;
            } else {
                av[i] = *(const float4*)(A + (size_t)(m0 + sa_m + i * 64) * K + k0 + sa_k);
            }
        }
        float4 bv[BIT];
#pragma unroll
        for (int i = 0; i < BIT; ++i) {
            const int f  = tid + i * 256;
            const int kl = f / (BN / 4);
            const int n4 = f - kl * (BN / 4);
            bv[i] = *(const float4*)(Wt + (size_t)(k0 + kl) * N + n0 + n4 * 4);
        }
        __syncthreads();
#pragma unroll
        for (int i = 0; i < AIT; ++i) {
            As[sa_k + 0][sa_m + i * 64] = av[i].x;
            As[sa_k + 1][sa_m + i * 64] = av[i].y;
            As[sa_k + 2][sa_m + i * 64] = av[i].z;
            As[sa_k + 3][sa_m + i * 64] = av[i].w;
        }
#pragma unroll
        for (int i = 0; i < BIT; ++i) {
            const int f  = tid + i * 256;
            const int kl = f / (BN / 4);
            const int n4 = f - kl * (BN / 4);
            *(float4*)&Bs[kl][n4 * 4] = bv[i];
        }
        __syncthreads();
#pragma unroll
        for (int kk = 0; kk < BK; ++kk) {
            float a[RT];
#pragma unroll
            for (int q = 0; q < RT / 4; ++q) {
                float4 t = *(const float4*)&As[kk][tm * RT + q * 4];
                a[q * 4 + 0] = t.x; a[q * 4 + 1] = t.y;
                a[q * 4 + 2] = t.z; a[q * 4 + 3] = t.w;
            }
            float b[NT];
#pragma unroll
            for (int q = 0; q < NT / 4; ++q) {
                float4 t = *(const float4*)&Bs[kk][tn * NT + q * 4];
                b[q * 4 + 0] = t.x; b[q * 4 + 1] = t.y;
                b[q * 4 + 2] = t.z; b[q * 4 + 3] = t.w;
            }
#pragma unroll
            for (int r = 0; r < RT; ++r)
#pragma unroll
                for (int c = 0; c < NT; ++c)
                    acc[r][c] = fmaf(a[r], b[c], acc[r][c]);
        }
    }

#pragma unroll
    for (int c = 0; c < NT; ++c) {
        const int n = n0 + tn * NT + c;
        const float bz = bias[n];
        const float sc = (n < qcols) ? qscale : 1.f;
#pragma unroll
        for (int r = 0; r < RT; ++r) acc[r][c] = (acc[r][c] + bz) * sc;
    }
    if (TRANS) {
#pragma unroll
        for (int c = 0; c < NT; ++c) {
            const int n = n0 + tn * NT + c;
            float* op = out + (size_t)n * M + m0 + tm * RT;
#pragma unroll
            for (int q = 0; q < RT / 4; ++q)
                *(float4*)(op + q * 4) = make_float4(acc[q * 4][c], acc[q * 4 + 1][c],
                                                     acc[q * 4 + 2][c], acc[q * 4 + 3][c]);
        }
    } else {
#pragma unroll
        for (int r = 0; r < RT; ++r) {
            float* op = out + (size_t)(m0 + tm * RT + r) * N + n0 + tn * NT;
#pragma unroll
            for (int q = 0; q < NT / 4; ++q)
                *(float4*)(op + q * 4) = make_float4(acc[r][q * 4], acc[r][q * 4 + 1],
                                                     acc[r][q * 4 + 2], acc[r][q * 4 + 3]);
        }
    }
}

template <int VPL>
__device__ inline void loadv(const float* __restrict__ p, float* d) {
    if constexpr (VPL == 2) {
        float2 t = *(const float2*)p;
        d[0] = t.x; d[1] = t.y;
    } else if constexpr (VPL == 4) {
        float4 t = *(const float4*)p;
        d[0] = t.x; d[1] = t.y; d[2] = t.z; d[3] = t.w;
    } else {
        float4 t0 = *(const float4*)p;
        float4 t1 = *(const float4*)(p + 4);
        d[0] = t0.x; d[1] = t0.y; d[2] = t0.z; d[3] = t0.w;
        d[4] = t1.x; d[5] = t1.y; d[6] = t1.z; d[7] = t1.w;
    }
}

// Fused neighborhood attention + proj. 256 thr = 4 waves x 4 px.
// Proj phase: BK=32 weight tiles (half the barriers of BK=16).
template <int C, int TRANS>
__global__ __launch_bounds__(256) void na2d_proj(
        const float* __restrict__ qkv, const float* __restrict__ rpb,
        const float* __restrict__ Wp, const float* __restrict__ bp,
        float* __restrict__ out, int H, int W, int M) {
    constexpr int VPL = C / 16;
    constexpr int NT  = C / 16;
    __shared__ float att_s[16][C + 4];
    __shared__ float Bs[32][C];
    const int tid  = threadIdx.x;
    const int blk  = xcd_swz(blockIdx.x, gridDim.x);  // L2 locality: 25x K/V reuse
    const int lane = tid & 63;
    const int g    = lane >> 4;
    const int li   = lane & 15;
    const int wave = tid >> 6;
    const int lp   = wave * 4 + g;
    const int pix  = blk * 16 + lp;
    const int h = pix / W;
    const int w = pix - h * W;
    const int h0 = min(max(h - 2, 0), H - 5);
    const int w0 = min(max(w - 2, 0), W - 5);
    const int cb = li * VPL;
    const int bih = h0 - h + 4;
    const int biw = w0 - w + 4;

    float qf[VPL];
    loadv<VPL>(qkv + (size_t)pix * (3 * C) + cb, qf);

    float p[25];
#pragma unroll
    for (int jr = 0; jr < 5; ++jr) {
        const float* rowk = qkv + (size_t)((h0 + jr) * W + w0) * (3 * C) + C + cb;
        float kf[5][VPL];
#pragma unroll
        for (int jc = 0; jc < 5; ++jc) loadv<VPL>(rowk + jc * 3 * C, kf[jc]);
#pragma unroll
        for (int jc = 0; jc < 5; ++jc) {
            float s = qf[0] * kf[jc][0];
#pragma unroll
            for (int v = 1; v < VPL; ++v) s = fmaf(qf[v], kf[jc][v], s);
            p[jr * 5 + jc] = s;
        }
    }
#pragma unroll
    for (int jr = 0; jr < 5; ++jr)
#pragma unroll
        for (int jc = 0; jc < 5; ++jc) {
            const int j = jr * 5 + jc;
            float v = p[j];
            v += __shfl_xor(v, 1);
            v += __shfl_xor(v, 2);
            v += __shfl_xor(v, 4);
            v += __shfl_xor(v, 8);
            p[j] = v + rpb[(bih + jr) * 9 + (biw + jc)];
        }
    float mx = p[0];
#pragma unroll
    for (int j = 1; j < 25; ++j) mx = fmaxf(mx, p[j]);
    float sum = 0.f;
#pragma unroll
    for (int j = 0; j < 25; ++j) {
        p[j] = expf(p[j] - mx);
        sum += p[j];
    }
    const float inv = 1.f / sum;

    float a[VPL];
#pragma unroll
    for (int v = 0; v < VPL; ++v) a[v] = 0.f;
#pragma unroll
    for (int jr = 0; jr < 5; ++jr) {
        const float* rowv = qkv + (size_t)((h0 + jr) * W + w0) * (3 * C) + 2 * C + cb;
        float vf[5][VPL];
#pragma unroll
        for (int jc = 0; jc < 5; ++jc) loadv<VPL>(rowv + jc * 3 * C, vf[jc]);
#pragma unroll
        for (int jc = 0; jc < 5; ++jc)
#pragma unroll
            for (int v = 0; v < VPL; ++v) a[v] = fmaf(p[jr * 5 + jc], vf[jc][v], a[v]);
    }
#pragma unroll
    for (int v = 0; v < VPL; ++v) att_s[lp][cb + v] = a[v] * inv;

    // ---- proj: 16xC @ CxC + bias; BK=32 tiles ----
    const int tm = tid & 15;
    const int tn = tid >> 4;
    constexpr int WPT = C / 8;             // floats staged per thread per tile
    const int skl = tid >> 3;              // k-row 0..31
    const int snn = (tid & 7) * WPT;       // col base
    float acc[NT];
#pragma unroll
    for (int c = 0; c < NT; ++c) acc[c] = bp[tn * NT + c];

#pragma unroll
    for (int k0 = 0; k0 < C; k0 += 32) {
        float tmp[WPT];
        {
            const float* src = Wp + (size_t)(k0 + skl) * C + snn;
#pragma unroll
            for (int t = 0; t < WPT; ++t) tmp[t] = src[t];
        }
        __syncthreads();   // prev tile's Bs reads done; iter0: att_s visible
#pragma unroll
        for (int t = 0; t < WPT; ++t) Bs[skl][snn + t] = tmp[t];
        __syncthreads();
#pragma unroll
        for (int kk = 0; kk < 32; ++kk) {
            const float av = att_s[tm][k0 + kk];
            const float* bsp = &Bs[kk][tn * NT];
#pragma unroll
            for (int c = 0; c < NT; ++c) acc[c] = fmaf(av, bsp[c], acc[c]);
        }
    }

    const int m0 = blk * 16;
    if (TRANS) {
#pragma unroll
        for (int c = 0; c < NT; ++c)
            out[(size_t)(tn * NT + c) * M + m0 + tm] = acc[c];
    } else {
        float* op = out + (size_t)(m0 + tm) * C + tn * NT;
#pragma unroll
        for (int c = 0; c < NT; ++c) op[c] = acc[c];
    }
}

extern "C" void kernel_launch(void* const* d_in, const int* in_sizes, int n_in,
                              void* d_out, int out_size, void* d_ws, size_t ws_size,
                              hipStream_t stream) {
    const float* attn    = (const float*)d_in[0];
    const float* w_qkv1  = (const float*)d_in[1];
    const float* b_qkv1  = (const float*)d_in[2];
    const float* w_proj1 = (const float*)d_in[3];
    const float* b_proj1 = (const float*)d_in[4];
    const float* rpb1    = (const float*)d_in[5];
    const float* w_qkv2  = (const float*)d_in[6];
    const float* b_qkv2  = (const float*)d_in[7];
    const float* w_proj2 = (const float*)d_in[8];
    const float* b_proj2 = (const float*)d_in[9];
    const float* rpb2    = (const float*)d_in[10];
    const float* w_qkv3  = (const float*)d_in[11];
    const float* b_qkv3  = (const float*)d_in[12];
    const float* w_proj3 = (const float*)d_in[13];
    const float* b_proj3 = (const float*)d_in[14];
    const float* rpb3    = (const float*)d_in[15];
    const float* w_up1   = (const float*)d_in[16];
    const float* b_up1   = (const float*)d_in[17];
    const float* w_up2   = (const float*)d_in[18];
    const float* b_up2   = (const float*)d_in[19];
    float* out = (float*)d_out;

    float* ws   = (float*)d_ws;
    float* bufB = ws + 2359296;              // qkv   (max 18432*384)
    float* bufD = bufB + 7077888;            // y     (max 4608*64)
    float* wc1  = bufD + 294912;             // 32x192 composed up1->qkv2
    float* bc1  = wc1 + 6144;                // 192
    float* wc2  = bc1 + 192;                 // 64x384 composed up2->qkv3
    float* bc2  = wc2 + 24576;               // 384

    // weight composition (weights only)
    compose2<<<(33 * 192 + 65 * 384 + 255) / 256, 256, 0, stream>>>(
        w_up1, b_up1, w_qkv2, b_qkv2, w_up2, b_up2, w_qkv3, b_qkv3,
        wc1, bc1, wc2, bc2);

    // ---- Stage 1: C=32, 24x48, M=1152 ----
    {
        const int H = 24, W = 48, C = 32, M = H * W;
        mm_bias<16, 1><<<M / 16, 3 * C, 16 * C * 4, stream>>>(
            attn, w_qkv1, b_qkv1, bufB, M, C, 3 * C, C, 1.f / sqrtf((float)C));
        na2d_proj<32, 0><<<M / 16, 256, 0, stream>>>(
            bufB, rpb1, w_proj1, b_proj1, bufD, H, W, M);
    }
    // ---- Stage 2: C=64, 48x96, M=4608; qkv2 = up2x(y1) @ wc1 + bc1 ----
    {
        const int H = 48, W = 96, C = 64, M = H * W;
        gemm_rt<64, 64, 4, 0, 1><<<dim3(M / 64, 3), 256, 0, stream>>>(
            bufD, wc1, bc1, bufB, M, 32, 3 * C, C, 1.f / sqrtf((float)C), 24, 48);
        na2d_proj<64, 0><<<M / 16, 256, 0, stream>>>(
            bufB, rpb2, w_proj2, b_proj2, bufD, H, W, M);
    }
    // ---- Stage 3: C=128, 96x192, M=18432; qkv3 = up2x(y2) @ wc2 + bc2 ----
    {
        const int H = 96, W = 192, C = 128, M = H * W;
        gemm_rt<128, 128, 8, 0, 1><<<dim3(M / 128, 3), 256, 0, stream>>>(
            bufD, wc2, bc2, bufB, M, 64, 3 * C, C, 1.f / sqrtf((float)C), 48, 96);
        na2d_proj<128, 1><<<M / 16, 256, 0, stream>>>(
            bufB, rpb3, w_proj3, b_proj3, out, H, W, M);  // -> CHW
    }
}